// Round 4
// baseline (427.274 us; speedup 1.0000x reference)
//
#include <hip/hip_runtime.h>

// AdaptiveGraph on MI355X.
// K1: Z = X W^T via bf16 MFMA with hi/lo split (fp32-accurate); writes Zb [n][h] + ZbT [h][n] bf16.
// K2: rowsum[r] = sum_c relu(Z_r . Z_c). LDS-free: MFMA frags loaded straight from L2-resident Zb.
// K3: recompute S^T tiles (frags from global), A = relu(S)*rsinv -> nt float4 stores (deferred
//     past the barrier for drain overlap), P through double-buffered LDS (1 barrier/iter),
//     out += P @ Z via second MFMA (B-frags from global ZbT), atomicAdd into d_out.

#define NR 8192
#define KD 256
#define HD 128

typedef short v8s __attribute__((ext_vector_type(8)));
typedef float v4f __attribute__((ext_vector_type(4)));

static __device__ __forceinline__ ushort f2bf(float f) {
    union { float f; unsigned u; } c; c.f = f;
    unsigned u = c.u;
    u += 0x7fffu + ((u >> 16) & 1u);  // RNE; inputs finite
    return (ushort)(u >> 16);
}
static __device__ __forceinline__ float bf2f(ushort b) {
    union { unsigned u; float f; } c; c.u = ((unsigned)b) << 16; return c.f;
}
static __device__ __forceinline__ unsigned pk2(float a, float b) {
    union { float f; unsigned u; } x, y; x.f = a; y.f = b;
    unsigned ua = x.u + 0x7fffu + ((x.u >> 16) & 1u);
    unsigned ub = y.u + 0x7fffu + ((y.u >> 16) & 1u);
    return (ua >> 16) | (ub & 0xffff0000u);
}

// ---------------- K1: Z = X @ W^T (MFMA, hi/lo bf16 split) ----------------
__global__ __launch_bounds__(256) void k_z(const float* __restrict__ X,
                                           const float* __restrict__ W,
                                           ushort* __restrict__ Zb,
                                           ushort* __restrict__ ZbT) {
    __shared__ ushort Xhi[32][264];
    __shared__ ushort Xlo[32][264];
    int tid = threadIdx.x, lane = tid & 63, wave = tid >> 6;
    int lm = lane & 15, lq = lane >> 4;
    int n0 = blockIdx.x * 32;
    int hbase = wave * 32;
    v8s Whi[2][8], Wlo[2][8];
#pragma unroll
    for (int hi = 0; hi < 2; ++hi) {
        const float* wp = W + (hbase + hi * 16 + lm) * KD + lq * 8;
#pragma unroll
        for (int ks = 0; ks < 8; ++ks) {
            float4 w0 = *(const float4*)(wp + ks * 32);
            float4 w1 = *(const float4*)(wp + ks * 32 + 4);
            float wv[8] = {w0.x, w0.y, w0.z, w0.w, w1.x, w1.y, w1.z, w1.w};
#pragma unroll
            for (int j = 0; j < 8; ++j) {
                ushort h = f2bf(wv[j]);
                Whi[hi][ks][j] = (short)h;
                Wlo[hi][ks][j] = (short)f2bf(wv[j] - bf2f(h));
            }
        }
    }
#pragma unroll
    for (int t = 0; t < 8; ++t) {
        int idx = tid + t * 256;
        int r = idx >> 6, c4 = (idx & 63) * 4;
        float4 x = *(const float4*)(X + (size_t)(n0 + r) * KD + c4);
        ushort h0 = f2bf(x.x), h1 = f2bf(x.y), h2 = f2bf(x.z), h3 = f2bf(x.w);
        unsigned a = ((unsigned)h0) | ((unsigned)h1 << 16);
        unsigned b = ((unsigned)h2) | ((unsigned)h3 << 16);
        unsigned c = ((unsigned)f2bf(x.x - bf2f(h0))) | ((unsigned)f2bf(x.y - bf2f(h1)) << 16);
        unsigned d = ((unsigned)f2bf(x.z - bf2f(h2))) | ((unsigned)f2bf(x.w - bf2f(h3)) << 16);
        *(uint2*)&Xhi[r][c4] = make_uint2(a, b);
        *(uint2*)&Xlo[r][c4] = make_uint2(c, d);
    }
    __syncthreads();
#pragma unroll
    for (int ni = 0; ni < 2; ++ni) {
        v8s Ah[8], Al[8];
#pragma unroll
        for (int ks = 0; ks < 8; ++ks) {
            Ah[ks] = *(const v8s*)&Xhi[ni * 16 + lm][ks * 32 + lq * 8];
            Al[ks] = *(const v8s*)&Xlo[ni * 16 + lm][ks * 32 + lq * 8];
        }
        v4f acc[2] = {{0.f, 0.f, 0.f, 0.f}, {0.f, 0.f, 0.f, 0.f}};
#pragma unroll
        for (int ks = 0; ks < 8; ++ks)
#pragma unroll
            for (int hi = 0; hi < 2; ++hi) {
                acc[hi] = __builtin_amdgcn_mfma_f32_16x16x32_bf16(Ah[ks], Whi[hi][ks], acc[hi], 0, 0, 0);
                acc[hi] = __builtin_amdgcn_mfma_f32_16x16x32_bf16(Ah[ks], Wlo[hi][ks], acc[hi], 0, 0, 0);
                acc[hi] = __builtin_amdgcn_mfma_f32_16x16x32_bf16(Al[ks], Whi[hi][ks], acc[hi], 0, 0, 0);
            }
#pragma unroll
        for (int hi = 0; hi < 2; ++hi) {
            int h = hbase + hi * 16 + lm;
            int nb = n0 + ni * 16 + lq * 4;
            ushort b0 = f2bf(acc[hi][0]), b1 = f2bf(acc[hi][1]);
            ushort b2 = f2bf(acc[hi][2]), b3 = f2bf(acc[hi][3]);
            Zb[(size_t)(nb + 0) * HD + h] = b0;
            Zb[(size_t)(nb + 1) * HD + h] = b1;
            Zb[(size_t)(nb + 2) * HD + h] = b2;
            Zb[(size_t)(nb + 3) * HD + h] = b3;
            *(uint2*)&ZbT[(size_t)h * NR + nb] =
                make_uint2(((unsigned)b0) | ((unsigned)b1 << 16), ((unsigned)b2) | ((unsigned)b3 << 16));
        }
    }
}

// ---------------- K2: rowsum (LDS-free) ----------------
// grid 512 = 64 rb x 8 cs; wave = 64r (wr2) x 64c (wc2) slice of a 128x128 tile; 8 c-iters.
__global__ __launch_bounds__(256) void k_rowsum(const ushort* __restrict__ Zb,
                                                float* __restrict__ rowsum) {
    int tid = threadIdx.x, lane = tid & 63, wave = tid >> 6;
    int lm = lane & 15, lq = lane >> 4;
    int rb = blockIdx.x >> 3, cs = blockIdx.x & 7;
    int row0 = rb * 128, cstart = cs * 1024;
    int wr2 = wave >> 1, wc2 = wave & 1;
    v8s Bfr[4][4];  // reg-cached row frags (B-operand for S^T), straight from global
#pragma unroll
    for (int ri = 0; ri < 4; ++ri)
#pragma unroll
        for (int ks = 0; ks < 4; ++ks)
            Bfr[ri][ks] = *(const v8s*)(Zb + (size_t)(row0 + wr2 * 64 + ri * 16 + lm) * HD + ks * 32 + lq * 8);
    float rs[4] = {0.f, 0.f, 0.f, 0.f};
    for (int it = 0; it < 8; ++it) {
        int c0 = cstart + it * 128 + wc2 * 64;
#pragma unroll
        for (int ci = 0; ci < 4; ++ci) {
            v8s Af[4];
#pragma unroll
            for (int ks = 0; ks < 4; ++ks)
                Af[ks] = *(const v8s*)(Zb + (size_t)(c0 + ci * 16 + lm) * HD + ks * 32 + lq * 8);
            v4f acc[4] = {{0.f,0.f,0.f,0.f},{0.f,0.f,0.f,0.f},{0.f,0.f,0.f,0.f},{0.f,0.f,0.f,0.f}};
#pragma unroll
            for (int ks = 0; ks < 4; ++ks)
#pragma unroll
                for (int ri = 0; ri < 4; ++ri)
                    acc[ri] = __builtin_amdgcn_mfma_f32_16x16x32_bf16(Af[ks], Bfr[ri][ks], acc[ri], 0, 0, 0);
#pragma unroll
            for (int ri = 0; ri < 4; ++ri)
                rs[ri] += fmaxf(acc[ri][0], 0.f) + fmaxf(acc[ri][1], 0.f) +
                          fmaxf(acc[ri][2], 0.f) + fmaxf(acc[ri][3], 0.f);
        }
    }
#pragma unroll
    for (int ri = 0; ri < 4; ++ri) {
        float v = rs[ri];
        v += __shfl_xor(v, 16, 64);
        v += __shfl_xor(v, 32, 64);
        if (lq == 0) atomicAdd(&rowsum[row0 + wr2 * 64 + ri * 16 + lm], v);
    }
}

// ---------------- K3: A write + out accumulate ----------------
// grid 512 = 128 rb x 4 cs; block 64r x (32 iters x 64c); wave = 32r x 32c (S^T) / 32r x 64h (U).
// LDS only for P transform (dbuf); 1 barrier/iter; A-stores deferred past barrier.
__global__ __launch_bounds__(256) void k_main(const ushort* __restrict__ Zb,
                                              const ushort* __restrict__ ZbT,
                                              const float* __restrict__ rowsum,
                                              float* __restrict__ outp,
                                              float* __restrict__ Ap) {
    __shared__ ushort PT[2][64][72];  // normalized A tile bf16, [r][c], double-buffered
    int tid = threadIdx.x, lane = tid & 63, wave = tid >> 6;
    int lm = lane & 15, lq = lane >> 4;
    int rb = blockIdx.x >> 2, cs = blockIdx.x & 3;
    int row0 = rb * 64, colb = cs * 2048;
    int wr2 = wave >> 1, wc2 = wave & 1;
    v8s Bfr[2][4];  // reg-cached ZR row-frags from global
#pragma unroll
    for (int ri = 0; ri < 2; ++ri)
#pragma unroll
        for (int ks = 0; ks < 4; ++ks)
            Bfr[ri][ks] = *(const v8s*)(Zb + (size_t)(row0 + wr2 * 32 + ri * 16 + lm) * HD + ks * 32 + lq * 8);
    float rsv[2];
#pragma unroll
    for (int ri = 0; ri < 2; ++ri)
        rsv[ri] = 1.0f / (rowsum[row0 + wr2 * 32 + ri * 16 + lm] + 1e-6f);
    v4f U[2][4];
#pragma unroll
    for (int ri = 0; ri < 2; ++ri)
#pragma unroll
        for (int hi = 0; hi < 4; ++hi) U[ri][hi] = (v4f){0.f, 0.f, 0.f, 0.f};

    for (int it = 0; it < 32; ++it) {
        int c0 = colb + it * 64;
        int b = it & 1;
        v4f av[2][2];
        // ---- S^T phase: frags from global, PT write, av held in regs ----
#pragma unroll
        for (int ci = 0; ci < 2; ++ci) {
            v8s Af[4];
#pragma unroll
            for (int ks = 0; ks < 4; ++ks)
                Af[ks] = *(const v8s*)(Zb + (size_t)(c0 + wc2 * 32 + ci * 16 + lm) * HD + ks * 32 + lq * 8);
            v4f S0 = {0.f, 0.f, 0.f, 0.f}, S1 = {0.f, 0.f, 0.f, 0.f};
#pragma unroll
            for (int ks = 0; ks < 4; ++ks) {
                S0 = __builtin_amdgcn_mfma_f32_16x16x32_bf16(Af[ks], Bfr[0][ks], S0, 0, 0, 0);
                S1 = __builtin_amdgcn_mfma_f32_16x16x32_bf16(Af[ks], Bfr[1][ks], S1, 0, 0, 0);
            }
            int cb = wc2 * 32 + ci * 16 + lq * 4;
            v4f a0, a1;
            a0[0] = fmaxf(S0[0], 0.f) * rsv[0]; a0[1] = fmaxf(S0[1], 0.f) * rsv[0];
            a0[2] = fmaxf(S0[2], 0.f) * rsv[0]; a0[3] = fmaxf(S0[3], 0.f) * rsv[0];
            a1[0] = fmaxf(S1[0], 0.f) * rsv[1]; a1[1] = fmaxf(S1[1], 0.f) * rsv[1];
            a1[2] = fmaxf(S1[2], 0.f) * rsv[1]; a1[3] = fmaxf(S1[3], 0.f) * rsv[1];
            av[ci][0] = a0; av[ci][1] = a1;
            *(uint2*)&PT[b][wr2 * 32 + lm][cb] = make_uint2(pk2(a0[0], a0[1]), pk2(a0[2], a0[3]));
            *(uint2*)&PT[b][wr2 * 32 + 16 + lm][cb] = make_uint2(pk2(a1[0], a1[1]), pk2(a1[2], a1[3]));
        }
        __syncthreads();  // PT[b] visible; the ONLY barrier this iteration
        // ---- A stores (issued post-barrier: drain hidden under U-phase + next S-phase) ----
#pragma unroll
        for (int ci = 0; ci < 2; ++ci) {
            int cb = wc2 * 32 + ci * 16 + lq * 4;
            __builtin_nontemporal_store(av[ci][0], (v4f*)(Ap + (size_t)(row0 + wr2 * 32 + lm) * NR + c0 + cb));
            __builtin_nontemporal_store(av[ci][1], (v4f*)(Ap + (size_t)(row0 + wr2 * 32 + 16 + lm) * NR + c0 + cb));
        }
        // ---- U phase: P from LDS, B-frags from global ZbT ----
#pragma unroll
        for (int ks = 0; ks < 2; ++ks) {
            v8s P0 = *(const v8s*)&PT[b][wr2 * 32 + lm][ks * 32 + lq * 8];
            v8s P1 = *(const v8s*)&PT[b][wr2 * 32 + 16 + lm][ks * 32 + lq * 8];
#pragma unroll
            for (int hi = 0; hi < 4; ++hi) {
                v8s Bz = *(const v8s*)(ZbT + (size_t)(wc2 * 64 + hi * 16 + lm) * NR + c0 + ks * 32 + lq * 8);
                U[0][hi] = __builtin_amdgcn_mfma_f32_16x16x32_bf16(P0, Bz, U[0][hi], 0, 0, 0);
                U[1][hi] = __builtin_amdgcn_mfma_f32_16x16x32_bf16(P1, Bz, U[1][hi], 0, 0, 0);
            }
        }
    }
#pragma unroll
    for (int ri = 0; ri < 2; ++ri)
#pragma unroll
        for (int hi = 0; hi < 4; ++hi)
#pragma unroll
            for (int j = 0; j < 4; ++j)
                atomicAdd(&outp[(size_t)(row0 + wr2 * 32 + ri * 16 + lq * 4 + j) * HD +
                                wc2 * 64 + hi * 16 + lm],
                          U[ri][hi][j]);
}

extern "C" void kernel_launch(void* const* d_in, const int* in_sizes, int n_in,
                              void* d_out, int out_size, void* d_ws, size_t ws_size,
                              hipStream_t stream) {
    (void)in_sizes; (void)n_in; (void)out_size; (void)ws_size;
    const float* X = (const float*)d_in[0];
    const float* W = (const float*)d_in[1];
    float* outp = (float*)d_out;
    float* Ap = outp + (size_t)NR * HD;  // A follows out in d_out
    char* ws = (char*)d_ws;
    ushort* Zb = (ushort*)ws;                                 // 2 MB
    ushort* ZbT = (ushort*)(ws + (size_t)NR * HD * 2);        // 2 MB
    float* rowsum = (float*)(ws + (size_t)NR * HD * 4);       // 32 KB

    (void)hipMemsetAsync(outp, 0, (size_t)NR * HD * sizeof(float), stream);
    (void)hipMemsetAsync(rowsum, 0, NR * sizeof(float), stream);
    k_z<<<dim3(NR / 32), dim3(256), 0, stream>>>(X, W, Zb, ZbT);
    k_rowsum<<<dim3(512), dim3(256), 0, stream>>>(Zb, rowsum);
    k_main<<<dim3(512), dim3(256), 0, stream>>>(Zb, ZbT, rowsum, outp, Ap);
}